// Round 1
// baseline (221.759 us; speedup 1.0000x reference)
//
#include <hip/hip_runtime.h>
#include <math.h>

// YOLO decode: feat13 [256,255,13,13] + feat26 [256,255,26,26]
//   -> out [256, 3*169 + 3*676 = 2535, 85] fp32
// Per element:
//   c==0: (sigmoid(v)+gx)*stride      c==1: (sigmoid(v)+gy)*stride
//   c==2: exp(v)*ANCHOR_W             c==3: exp(v)*ANCHOR_H   (stride cancels)
//   c>=4: sigmoid(v)
//
// Block = 256 threads, one (b, anchor, 169-spatial-tile) per block.
// 13x13 head: 1 tile/plane (768 blocks); 26x26 head: 4 tiles/plane (3072 blocks).
// LDS tile [85 ch][169 spatial] = 57,460 B -> 2 blocks/CU.

#define BATCH 256
#define ROWS 2535  // 3*169 + 3*676

__device__ __forceinline__ float sigmoidf_(float v) {
    return 1.0f / (1.0f + __expf(-v));
}

__global__ __launch_bounds__(256) void yolo_decode_kernel(
    const float* __restrict__ f13,
    const float* __restrict__ f26,
    float* __restrict__ out)
{
    __shared__ float lds[85 * 169];

    const int bid = blockIdx.x;

    const float* src;   // start of this (b, anchor) channel-block (85*GG floats)
    int G, GG, s0, a, b, rowoff;
    float stride, aw, ah;

    if (bid < 768) {
        // 13x13 head, anchors (81,82),(135,169),(344,319), stride 32
        b = bid / 3;
        a = bid - b * 3;
        G = 13; GG = 169; s0 = 0; rowoff = 0; stride = 32.0f;
        src = f13 + ((size_t)b * 255 + (size_t)a * 85) * 169;
        aw = (a == 0) ? 81.0f : (a == 1) ? 135.0f : 344.0f;
        ah = (a == 0) ? 82.0f : (a == 1) ? 169.0f : 319.0f;
    } else {
        // 26x26 head, anchors (10,14),(23,27),(37,58), stride 16
        int t = bid - 768;
        b = t / 12;
        int r = t - b * 12;
        a = r >> 2;
        int tile = r & 3;
        G = 26; GG = 676; s0 = tile * 169; rowoff = 507; stride = 16.0f;
        src = f26 + ((size_t)b * 255 + (size_t)a * 85) * 676;
        aw = (a == 0) ? 10.0f : (a == 1) ? 23.0f : 37.0f;
        ah = (a == 0) ? 14.0f : (a == 1) ? 27.0f : 58.0f;
    }

    // ---- Load: 85 channels x 169 contiguous spatial values, coalesced ----
    for (int i = threadIdx.x; i < 85 * 169; i += 256) {
        int c = i / 169;
        int t = i - c * 169;
        lds[i] = src[(size_t)c * GG + s0 + t];
    }
    __syncthreads();

    // ---- Transposed compute + store: rows of 85 contiguous floats ----
    float* dst = out + ((size_t)b * ROWS + rowoff + (size_t)a * GG + s0) * 85;
    for (int i = threadIdx.x; i < 169 * 85; i += 256) {
        int t = i / 85;
        int c = i - t * 85;
        float v = lds[c * 169 + t];  // stride 169 floats -> bank step 9, conflict-free
        float r;
        if (c >= 4) {
            r = sigmoidf_(v);
        } else if (c < 2) {
            int s = s0 + t;
            float g = (c == 0) ? (float)(s % G) : (float)(s / G);
            r = (sigmoidf_(v) + g) * stride;
        } else {
            r = __expf(v) * ((c == 2) ? aw : ah);
        }
        dst[(size_t)t * 85 + c] = r;
    }
}

extern "C" void kernel_launch(void* const* d_in, const int* in_sizes, int n_in,
                              void* d_out, int out_size, void* d_ws, size_t ws_size,
                              hipStream_t stream) {
    const float* f13 = (const float*)d_in[0];
    const float* f26 = (const float*)d_in[1];
    float* out = (float*)d_out;
    // 768 blocks for 13x13 head + 3072 for 26x26 head
    yolo_decode_kernel<<<3840, 256, 0, stream>>>(f13, f26, out);
}

// Round 2
// 125.028 us; speedup vs baseline: 1.7737x; 1.7737x over previous
//
#include <hip/hip_runtime.h>

// YOLO decode: feat13 [256,255,13,13] + feat26 [256,255,26,26]
//   -> out [256, 2535, 85] fp32   (2535 = 3*169 + 3*676)
//
// Block = 256 threads. One block per (b, anchor, 64-wide spatial tile).
// LDS tile [85][65] = 22.1 KB -> 7 blocks/CU (28 waves/CU) vs 2 before.
// G is a template constant: all %G //G /TPP become magic multiplies.
// sigmoid = rcp(1+exp(-v)) via v_rcp_f32; exp(v) = rcp(exp(-v)) (reuse).

#define ROWS 2535

template<int G, int TPP, bool VEC4>
__global__ __launch_bounds__(256) void yolo_head(
    const float* __restrict__ f, float* __restrict__ out,
    const int rowoff, const float stride_,
    const float aw0, const float ah0, const float aw1, const float ah1,
    const float aw2, const float ah2)
{
    constexpr int GG = G * G;
    __shared__ float lds[85 * 65];

    const int bid  = blockIdx.x;
    const int tile = bid % TPP;        // TPP constexpr -> magic mul
    const int ba   = bid / TPP;
    const int a    = ba % 3;
    const int b    = ba / 3;
    const int s0   = tile * 64;
    const int W    = (GG - s0 < 64) ? (GG - s0) : 64;

    const float aw = (a == 0) ? aw0 : (a == 1) ? aw1 : aw2;
    const float ah = (a == 0) ? ah0 : (a == 1) ? ah1 : ah2;

    const float* __restrict__ src = f + (size_t)(b * 255 + a * 85) * GG;

    // ---- Load: 85 channels x W contiguous spatial values, coalesced ----
    if (VEC4) {
        // channel stride GG*4 bytes is 16B-aligned (676*4=2704), s0*4 = 256B
        const int W4 = W >> 2;   // 16 full tile, 9 tail (36/4)
        for (int i = threadIdx.x; i < 85 * 16; i += 256) {
            int c = i >> 4, w4 = i & 15;
            if (w4 < W4) {
                const float4 v = *(const float4*)(src + (size_t)c * GG + s0 + w4 * 4);
                int base = c * 65 + w4 * 4;
                lds[base + 0] = v.x; lds[base + 1] = v.y;
                lds[base + 2] = v.z; lds[base + 3] = v.w;
            }
        }
    } else {
        for (int i = threadIdx.x; i < 85 * 64; i += 256) {
            int c = i >> 6, w = i & 63;
            if (w < W)
                lds[c * 65 + w] = src[(size_t)c * GG + s0 + w];
        }
    }
    __syncthreads();

    // ---- Transposed compute + store: contiguous W*85 floats ----
    float* __restrict__ dst = out + ((size_t)b * ROWS + rowoff + (size_t)a * GG + s0) * 85;
    const int n = W * 85;
    for (int i = threadIdx.x; i < n; i += 256) {
        int t = i / 85;              // constant divisor -> magic mul
        int c = i - t * 85;
        float v = lds[c * 65 + t];   // lane-consecutive c -> bank step 1, conflict-free
        float e  = __expf(-v);
        float sg = __builtin_amdgcn_rcpf(1.0f + e);
        float r;
        if (c >= 4) {
            r = sg;                                    // conf + 80 classes
        } else if (c < 2) {
            int s = s0 + t;
            float g = (c == 0) ? (float)(s % G) : (float)(s / G);   // constexpr G
            r = (sg + g) * stride_;
        } else {
            r = __builtin_amdgcn_rcpf(e) * ((c == 2) ? aw : ah);    // exp(v)*anchor
        }
        dst[i] = r;                  // i = t*85 + c, coalesced
    }
}

extern "C" void kernel_launch(void* const* d_in, const int* in_sizes, int n_in,
                              void* d_out, int out_size, void* d_ws, size_t ws_size,
                              hipStream_t stream) {
    const float* f13 = (const float*)d_in[0];
    const float* f26 = (const float*)d_in[1];
    float* out = (float*)d_out;

    // 13x13 head: stride 32, anchors (81,82),(135,169),(344,319); ceil(169/64)=3 tiles
    yolo_head<13, 3, false><<<256 * 3 * 3, 256, 0, stream>>>(
        f13, out, 0, 32.0f, 81.0f, 82.0f, 135.0f, 169.0f, 344.0f, 319.0f);
    // 26x26 head: stride 16, anchors (10,14),(23,27),(37,58); ceil(676/64)=11 tiles
    yolo_head<26, 11, true><<<256 * 3 * 11, 256, 0, stream>>>(
        f26, out, 507, 16.0f, 10.0f, 14.0f, 23.0f, 27.0f, 37.0f, 58.0f);
}

// Round 3
// 112.241 us; speedup vs baseline: 1.9757x; 1.1139x over previous
//
#include <hip/hip_runtime.h>

// YOLO decode, fused: feat13 [256,255,13,13] + feat26 [256,255,26,26]
//   -> out [256, 2535, 85] fp32   (2535 = 3*169 + 3*676)
//
// One kernel, 10752 blocks of 256. Block = (b, anchor, 64-wide spatial tile);
// head26 blocks first (long pole starts immediately).
//
// LDS holds the OUTPUT-layout tile: lds[mis + w*85 + c] (21.8 KB -> 7 blk/CU).
//   - staging writes: stride 85 floats between lanes -> bank step 21 (odd),
//     conflict-free
//   - compute reads: contiguous ds_read_b128 (canonical pattern)
//   - stores: aligned global_store_dwordx4 ('mis' shift keeps LDS reads AND
//     global stores 16B-aligned; <=3 prologue/tail elems scalar)

#define ROWS 2535
#define H26_BLOCKS (256 * 3 * 11)   // ceil(676/64) = 11 tiles
#define H13_BLOCKS (256 * 3 * 3)    // ceil(169/64) = 3 tiles

template<int G>
__device__ __forceinline__ float decode_one(float v, int j, int s0,
                                            float stride_, float aw, float ah)
{
    int t = j / 85;              // constant divisor -> magic mul
    int c = j - t * 85;
    float e  = __expf(-v);
    float sg = __builtin_amdgcn_rcpf(1.0f + e);     // sigmoid(v)
    if (c >= 4) return sg;                          // conf + 80 classes
    if (c < 2) {
        int s = s0 + t;
        float g = (c == 0) ? (float)(s % G) : (float)(s / G);  // constexpr G
        return (sg + g) * stride_;
    }
    return __builtin_amdgcn_rcpf(e) * ((c == 2) ? aw : ah);    // exp(v)*anchor
}

template<int G, int TPP, bool VEC4>
__device__ __forceinline__ void head_body(
    const float* __restrict__ f, float* __restrict__ out, float* __restrict__ lds,
    int bid, int rowoff, float stride_,
    float aw0, float ah0, float aw1, float ah1, float aw2, float ah2)
{
    constexpr int GG = G * G;
    const int tile = bid % TPP;        // constexpr divisor
    const int ba   = bid / TPP;
    const int a    = ba % 3;
    const int b    = ba / 3;
    const int s0   = tile * 64;
    const int W    = (GG - s0 < 64) ? (GG - s0) : 64;

    const float aw = (a == 0) ? aw0 : (a == 1) ? aw1 : aw2;
    const float ah = (a == 0) ? ah0 : (a == 1) ? ah1 : ah2;

    const float* __restrict__ src = f + (size_t)(b * 255 + a * 85) * GG;
    float* __restrict__ dst = out + ((size_t)b * ROWS + rowoff + (size_t)a * GG + s0) * 85;

    const int mis = (int)(((size_t)dst >> 2) & 3);  // float misalignment of dst

    // ---- Stage global -> LDS (output layout, shifted by mis) ----
    if (VEC4) {
        // W is 64 or 36: always a multiple of 4. Channel base 16B-aligned
        // (GG*4 = 2704, s0*4 = 256-multiple).
        const int W4 = W >> 2;
        for (int i = threadIdx.x; i < 85 * 16; i += 256) {
            int c = i >> 4, w4 = i & 15;
            if (w4 < W4) {
                const float4 v = *(const float4*)(src + (size_t)c * GG + s0 + w4 * 4);
                int base = mis + (w4 * 4) * 85 + c;
                lds[base]       = v.x;
                lds[base + 85]  = v.y;
                lds[base + 170] = v.z;
                lds[base + 255] = v.w;
            }
        }
    } else {
        for (int i = threadIdx.x; i < 85 * 64; i += 256) {
            int c = i >> 6, w = i & 63;
            if (w < W)
                lds[mis + w * 85 + c] = src[(size_t)c * GG + s0 + w];
        }
    }
    __syncthreads();

    // ---- Decode + store ----
    const int n  = W * 85;
    const int k  = (4 - mis) & 3;      // scalar prologue so dst+k is 16B-aligned
    const int nq = (n - k) >> 2;

    if (threadIdx.x < k)               // prologue (<=3 elems)
        dst[threadIdx.x] = decode_one<G>(lds[mis + threadIdx.x], threadIdx.x,
                                         s0, stride_, aw, ah);

    for (int q = threadIdx.x; q < nq; q += 256) {
        int j0 = q * 4 + k;
        const float4 in = *(const float4*)(lds + mis + j0);  // 16B-aligned
        float4 r;
        r.x = decode_one<G>(in.x, j0 + 0, s0, stride_, aw, ah);
        r.y = decode_one<G>(in.y, j0 + 1, s0, stride_, aw, ah);
        r.z = decode_one<G>(in.z, j0 + 2, s0, stride_, aw, ah);
        r.w = decode_one<G>(in.w, j0 + 3, s0, stride_, aw, ah);
        *(float4*)(dst + j0) = r;                            // 16B-aligned
    }

    for (int j = k + nq * 4 + threadIdx.x; j < n; j += 256)  // tail (<=3 elems)
        dst[j] = decode_one<G>(lds[mis + j], j, s0, stride_, aw, ah);
}

__global__ __launch_bounds__(256) void yolo_fused(
    const float* __restrict__ f13, const float* __restrict__ f26,
    float* __restrict__ out)
{
    __shared__ float lds[64 * 85 + 4];   // +4: 'mis' shift headroom
    const int bid = blockIdx.x;
    if (bid < H26_BLOCKS) {
        head_body<26, 11, true>(f26, out, lds, bid, 507, 16.0f,
                                10.0f, 14.0f, 23.0f, 27.0f, 37.0f, 58.0f);
    } else {
        head_body<13, 3, false>(f13, out, lds, bid - H26_BLOCKS, 0, 32.0f,
                                81.0f, 82.0f, 135.0f, 169.0f, 344.0f, 319.0f);
    }
}

extern "C" void kernel_launch(void* const* d_in, const int* in_sizes, int n_in,
                              void* d_out, int out_size, void* d_ws, size_t ws_size,
                              hipStream_t stream) {
    const float* f13 = (const float*)d_in[0];
    const float* f26 = (const float*)d_in[1];
    float* out = (float*)d_out;
    yolo_fused<<<H26_BLOCKS + H13_BLOCKS, 256, 0, stream>>>(f13, f26, out);
}

// Round 5
// 98.598 us; speedup vs baseline: 2.2491x; 1.1384x over previous
//
#include <hip/hip_runtime.h>

// YOLO decode, fused: feat13 [256,255,13,13] + feat26 [256,255,26,26]
//   -> out [256, 2535, 85] fp32   (2535 = 3*169 + 3*676)
//
// One kernel, 10752 blocks of 256. Block = (b, anchor, 64-wide spatial tile);
// head26 blocks first (long pole starts immediately).
//
// LDS holds the OUTPUT-layout tile: lds[mis + w*85 + c] (21.8 KB -> 7 blk/CU).
//   - staging writes: stride 85 floats between lanes -> bank step 21 (odd),
//     conflict-free; compute reads contiguous ds_read_b128; global stores
//     aligned dwordx4.
//   - stores are NONTEMPORAL (native ext_vector_type for the builtin):
//     output (220 MB) must not evict the input (220 MB) from the 256 MB
//     Infinity Cache — R3 showed 159 MB/replay of input re-fetch from
//     store-side L3 pollution.

#define ROWS 2535
#define H26_BLOCKS (256 * 3 * 11)   // ceil(676/64) = 11 tiles
#define H13_BLOCKS (256 * 3 * 3)    // ceil(169/64) = 3 tiles

typedef float vf4 __attribute__((ext_vector_type(4)));

template<int G>
__device__ __forceinline__ float decode_one(float v, int j, int s0,
                                            float stride_, float aw, float ah)
{
    int t = j / 85;              // constant divisor -> magic mul
    int c = j - t * 85;
    float e  = __expf(-v);
    float sg = __builtin_amdgcn_rcpf(1.0f + e);     // sigmoid(v)
    if (c >= 4) return sg;                          // conf + 80 classes
    if (c < 2) {
        int s = s0 + t;
        float g = (c == 0) ? (float)(s % G) : (float)(s / G);  // constexpr G
        return (sg + g) * stride_;
    }
    return __builtin_amdgcn_rcpf(e) * ((c == 2) ? aw : ah);    // exp(v)*anchor
}

template<int G, int TPP, bool VEC4>
__device__ __forceinline__ void head_body(
    const float* __restrict__ f, float* __restrict__ out, float* __restrict__ lds,
    int bid, int rowoff, float stride_,
    float aw0, float ah0, float aw1, float ah1, float aw2, float ah2)
{
    constexpr int GG = G * G;
    const int tile = bid % TPP;        // constexpr divisor
    const int ba   = bid / TPP;
    const int a    = ba % 3;
    const int b    = ba / 3;
    const int s0   = tile * 64;
    const int W    = (GG - s0 < 64) ? (GG - s0) : 64;

    const float aw = (a == 0) ? aw0 : (a == 1) ? aw1 : aw2;
    const float ah = (a == 0) ? ah0 : (a == 1) ? ah1 : ah2;

    const float* __restrict__ src = f + (size_t)(b * 255 + a * 85) * GG;
    float* __restrict__ dst = out + ((size_t)b * ROWS + rowoff + (size_t)a * GG + s0) * 85;

    const int mis = (int)(((size_t)dst >> 2) & 3);  // float misalignment of dst

    // ---- Stage global -> LDS (output layout, shifted by mis) ----
    if (VEC4) {
        // W is 64 or 36: always a multiple of 4. Channel base 16B-aligned
        // (GG*4 = 2704, s0*4 = 256-multiple).
        const int W4 = W >> 2;
        for (int i = threadIdx.x; i < 85 * 16; i += 256) {
            int c = i >> 4, w4 = i & 15;
            if (w4 < W4) {
                const vf4 v = *(const vf4*)(src + (size_t)c * GG + s0 + w4 * 4);
                int base = mis + (w4 * 4) * 85 + c;
                lds[base]       = v.x;
                lds[base + 85]  = v.y;
                lds[base + 170] = v.z;
                lds[base + 255] = v.w;
            }
        }
    } else {
        for (int i = threadIdx.x; i < 85 * 64; i += 256) {
            int c = i >> 6, w = i & 63;
            if (w < W)
                lds[mis + w * 85 + c] = src[(size_t)c * GG + s0 + w];
        }
    }
    __syncthreads();

    // ---- Decode + store (nontemporal) ----
    const int n  = W * 85;
    const int k  = (4 - mis) & 3;      // scalar prologue so dst+k is 16B-aligned
    const int nq = (n - k) >> 2;

    if (threadIdx.x < k)               // prologue (<=3 elems)
        __builtin_nontemporal_store(
            decode_one<G>(lds[mis + threadIdx.x], threadIdx.x, s0, stride_, aw, ah),
            dst + threadIdx.x);

    for (int q = threadIdx.x; q < nq; q += 256) {
        int j0 = q * 4 + k;
        const vf4 in = *(const vf4*)(lds + mis + j0);  // 16B-aligned
        vf4 r;
        r.x = decode_one<G>(in.x, j0 + 0, s0, stride_, aw, ah);
        r.y = decode_one<G>(in.y, j0 + 1, s0, stride_, aw, ah);
        r.z = decode_one<G>(in.z, j0 + 2, s0, stride_, aw, ah);
        r.w = decode_one<G>(in.w, j0 + 3, s0, stride_, aw, ah);
        __builtin_nontemporal_store(r, (vf4*)(dst + j0));  // 16B-aligned, nt
    }

    for (int j = k + nq * 4 + threadIdx.x; j < n; j += 256)  // tail (<=3 elems)
        __builtin_nontemporal_store(
            decode_one<G>(lds[mis + j], j, s0, stride_, aw, ah), dst + j);
}

__global__ __launch_bounds__(256) void yolo_fused(
    const float* __restrict__ f13, const float* __restrict__ f26,
    float* __restrict__ out)
{
    __shared__ float lds[64 * 85 + 4];   // +4: 'mis' shift headroom
    const int bid = blockIdx.x;
    if (bid < H26_BLOCKS) {
        head_body<26, 11, true>(f26, out, lds, bid, 507, 16.0f,
                                10.0f, 14.0f, 23.0f, 27.0f, 37.0f, 58.0f);
    } else {
        head_body<13, 3, false>(f13, out, lds, bid - H26_BLOCKS, 0, 32.0f,
                                81.0f, 82.0f, 135.0f, 169.0f, 344.0f, 319.0f);
    }
}

extern "C" void kernel_launch(void* const* d_in, const int* in_sizes, int n_in,
                              void* d_out, int out_size, void* d_ws, size_t ws_size,
                              hipStream_t stream) {
    const float* f13 = (const float*)d_in[0];
    const float* f26 = (const float*)d_in[1];
    float* out = (float*)d_out;
    yolo_fused<<<H26_BLOCKS + H13_BLOCKS, 256, 0, stream>>>(f13, f26, out);
}

// Round 6
// 93.523 us; speedup vs baseline: 2.3712x; 1.0543x over previous
//
#include <hip/hip_runtime.h>

// YOLO decode, fused: feat13 [256,255,13,13] + feat26 [256,255,26,26]
//   -> out [256, 2535, 85] fp32   (2535 = 3*169 + 3*676)
//
// R6 structure:
//  - W=52 spatial tile: LDS 52*85*4 = 17.7 KB -> 8 blocks/CU (32 waves, 100%).
//    676 = 13*52 exactly (no ragged tiles in the big head); 169 = 3*52 + 13.
//  - Box channels (c<4, 4.7% of elems) are decoded DURING staging, where the
//    channel index is structural (no div) and 52 % 26 == 52 % 13 == 0 makes
//    grid coords trivial. LDS holds final values for c<4, raw for c>=4.
//  - Main loop is uniform: r = (c<4) ? lds : sigmoid(lds). One exp+rcp+cndmask
//    per element (R5 spent ~35% VALUBusy on per-element branchy double-
//    transcendental decode).
//  - LDS in output layout, shifted by dst misalignment 'mis': ds_read_b128 +
//    aligned nontemporal global_store_dwordx4.

#define ROWS 2535
#define H26_BLOCKS (256 * 3 * 13)   // 676/52 = 13 tiles
#define H13_BLOCKS (256 * 3 * 4)    // ceil(169/52) = 4 tiles (last W=13)

typedef float vf4 __attribute__((ext_vector_type(4)));

__device__ __forceinline__ float fsig(float v) {
    return __builtin_amdgcn_rcpf(1.0f + __expf(-v));
}

template<int G, int TPP, bool VEC4>
__device__ __forceinline__ void head_body(
    const float* __restrict__ f, float* __restrict__ out, float* __restrict__ lds,
    int bid, int rowoff, float stride_,
    float aw0, float ah0, float aw1, float ah1, float aw2, float ah2)
{
    constexpr int GG = G * G;
    const int tile = bid % TPP;        // constexpr divisor -> magic mul
    const int ba   = bid / TPP;
    const int a    = ba % 3;
    const int b    = ba / 3;
    const int s0   = tile * 52;
    const int W    = (GG - s0 < 52) ? (GG - s0) : 52;

    const float aw = (a == 0) ? aw0 : (a == 1) ? aw1 : aw2;
    const float ah = (a == 0) ? ah0 : (a == 1) ? ah1 : ah2;

    const float* __restrict__ src = f + (size_t)(b * 255 + a * 85) * GG;
    float* __restrict__ dst = out + ((size_t)b * ROWS + rowoff + (size_t)a * GG + s0) * 85;

    const int mis = (int)(((size_t)dst >> 2) & 3);  // float misalignment of dst

    // ---- Stage global -> LDS (output layout; box channels pre-decoded) ----
    if (VEC4) {
        // 26-head: W == 52 always. Channel base 16B-aligned
        // (GG*4 = 2704 = 169*16; s0*4 = tile*208 = tile*13*16).
        for (int i = threadIdx.x; i < 85 * 13; i += 256) {
            int c  = i / 13;           // constexpr divisor
            int w4 = i - c * 13;
            const vf4 v = *(const vf4*)(src + (size_t)c * GG + s0 + w4 * 4);
            int base = mis + (w4 * 4) * 85 + c;
            if (c >= 4) {
                lds[base]       = v.x;
                lds[base + 85]  = v.y;
                lds[base + 170] = v.z;
                lds[base + 255] = v.w;
            } else {
                #pragma unroll
                for (int e = 0; e < 4; ++e) {
                    int local = w4 * 4 + e;            // s0 % 26 == 0
                    float x = v[e];
                    float r;
                    if (c == 0) {
                        int gx = (local < G) ? local : local - G;
                        r = (fsig(x) + (float)gx) * stride_;
                    } else if (c == 1) {
                        int gy = tile * 2 + ((local >= G) ? 1 : 0);
                        r = (fsig(x) + (float)gy) * stride_;
                    } else {
                        r = __expf(x) * ((c == 2) ? aw : ah);
                    }
                    lds[base + e * 85] = r;
                }
            }
        }
    } else {
        // 13-head: scalar loads (channel stride 676 B breaks 16B alignment).
        for (int i = threadIdx.x; i < 85 * 52; i += 256) {
            int c = i / 52;            // constexpr divisor
            int w = i - c * 52;
            if (w < W) {
                float x = src[(size_t)c * GG + s0 + w];
                float r = x;
                if (c < 4) {
                    int t13 = w / 13;                  // 0..3, s0 % 13 == 0
                    int gx  = w - t13 * 13;
                    int gy  = tile * 4 + t13;
                    if (c == 0)      r = (fsig(x) + (float)gx) * stride_;
                    else if (c == 1) r = (fsig(x) + (float)gy) * stride_;
                    else             r = __expf(x) * ((c == 2) ? aw : ah);
                }
                lds[mis + w * 85 + c] = r;
            }
        }
    }
    __syncthreads();

    // ---- Uniform sigmoid + store (nontemporal) ----
    const int n  = W * 85;
    const int k  = (4 - mis) & 3;      // prologue so dst+k is 16B-aligned
    const int nq = (n - k) >> 2;

    if (threadIdx.x < k)               // j < 3 -> c = j < 4 -> pre-decoded
        __builtin_nontemporal_store(lds[mis + threadIdx.x], dst + threadIdx.x);

    for (int q = threadIdx.x; q < nq; q += 256) {
        int j0 = q * 4 + k;
        const vf4 in = *(const vf4*)(lds + mis + j0);  // 16B-aligned ds_read_b128
        int t0 = j0 / 85;              // magic mul, once per vec4
        int c0 = j0 - t0 * 85;
        vf4 r;
        #pragma unroll
        for (int e = 0; e < 4; ++e) {
            int c = c0 + e;
            c = (c >= 85) ? c - 85 : c;
            float x  = in[e];
            float sg = fsig(x);
            r[e] = (c < 4) ? x : sg;   // box channels already final
        }
        __builtin_nontemporal_store(r, (vf4*)(dst + j0));
    }

    for (int j = k + nq * 4 + threadIdx.x; j < n; j += 256) {   // tail <=3
        int tt = j / 85;
        int c  = j - tt * 85;
        float x  = lds[mis + j];
        float sg = fsig(x);
        __builtin_nontemporal_store((c < 4) ? x : sg, dst + j);
    }
}

__global__ __launch_bounds__(256) void yolo_fused(
    const float* __restrict__ f13, const float* __restrict__ f26,
    float* __restrict__ out)
{
    __shared__ float lds[52 * 85 + 4];   // 17.7 KB: 8 blocks/CU (wave-capped)
    const int bid = blockIdx.x;
    if (bid < H26_BLOCKS) {
        head_body<26, 13, true>(f26, out, lds, bid, 507, 16.0f,
                                10.0f, 14.0f, 23.0f, 27.0f, 37.0f, 58.0f);
    } else {
        head_body<13, 4, false>(f13, out, lds, bid - H26_BLOCKS, 0, 32.0f,
                                81.0f, 82.0f, 135.0f, 169.0f, 344.0f, 319.0f);
    }
}

extern "C" void kernel_launch(void* const* d_in, const int* in_sizes, int n_in,
                              void* d_out, int out_size, void* d_ws, size_t ws_size,
                              hipStream_t stream) {
    const float* f13 = (const float*)d_in[0];
    const float* f26 = (const float*)d_in[1];
    float* out = (float*)d_out;
    yolo_fused<<<H26_BLOCKS + H13_BLOCKS, 256, 0, stream>>>(f13, f26, out);
}

// Round 7
// 90.565 us; speedup vs baseline: 2.4486x; 1.0327x over previous
//
#include <hip/hip_runtime.h>

// YOLO decode, fused: feat13 [256,255,13,13] + feat26 [256,255,26,26]
//   -> out [256, 2535, 85] fp32   (2535 = 3*169 + 3*676)
//
// R7: attack memory-pipeline limits (traffic is compulsory).
//  - Staging loads BATCHED into registers (all issued before any LDS write):
//    4-9 loads in flight per wave instead of ~1 (serial load->ds_write chain).
//  - PAIR-CHANNEL staging: thread loads channels c,c+1 at same spatial w ->
//    LDS writes to adjacent dwords lds[base],lds[base+1] -> ds_write2_b32
//    merge (4B-aligned, valid under 'mis' shift). Halves LDS-write instrs.
//  - Box channels (c<4) decoded during staging (pairs p=0: bx/by, p=1: bw/bh).
//  - W=52 tile, LDS 17.7 KB output-layout, 8 blocks/CU; nt dwordx4 stores.

#define ROWS 2535
#define H26_BLOCKS (256 * 3 * 13)   // 676/52 = 13 tiles
#define H13_BLOCKS (256 * 3 * 4)    // ceil(169/52) = 4 tiles (last W=13)

typedef float vf4 __attribute__((ext_vector_type(4)));

__device__ __forceinline__ float fsig(float v) {
    return __builtin_amdgcn_rcpf(1.0f + __expf(-v));
}

__device__ __forceinline__ void store_phase(
    const float* __restrict__ lds, float* __restrict__ dst, int mis, int n)
{
    const int t  = threadIdx.x;
    const int kk = (4 - mis) & 3;
    const int nq = (n - kk) >> 2;
    if (t < kk)                       // prologue (<=3, c<4 -> pre-decoded)
        __builtin_nontemporal_store(lds[mis + t], dst + t);
    for (int q = t; q < nq; q += 256) {
        int j0 = q * 4 + kk;
        const vf4 in = *(const vf4*)(lds + mis + j0);   // 16B-aligned b128
        int t0 = j0 / 85;             // magic mul once per quad
        int c0 = j0 - t0 * 85;
        vf4 r;
        #pragma unroll
        for (int e = 0; e < 4; ++e) {
            int c = c0 + e; c = (c >= 85) ? c - 85 : c;
            float x = in[e];
            r[e] = (c < 4) ? x : fsig(x);               // box already final
        }
        __builtin_nontemporal_store(r, (vf4*)(dst + j0));
    }
    for (int j = kk + nq * 4 + t; j < n; j += 256) {    // tail (<=3)
        int tt = j / 85; int c = j - tt * 85;
        float x = lds[mis + j];
        __builtin_nontemporal_store((c < 4) ? x : fsig(x), dst + j);
    }
}

__device__ __forceinline__ void head26_body(
    const float* __restrict__ f, float* __restrict__ out, float* __restrict__ lds,
    int bid)
{
    constexpr int G = 26, GG = 676, TPP = 13;
    const int tile = bid % TPP;       // constexpr divisors -> magic mul
    const int ba   = bid / TPP;
    const int a    = ba % 3;
    const int b    = ba / 3;
    const int s0   = tile * 52;       // s0 % 26 == 0

    const float aw = (a == 0) ? 10.f : (a == 1) ? 23.f : 37.f;
    const float ah = (a == 0) ? 14.f : (a == 1) ? 27.f : 58.f;

    const float* __restrict__ src = f + (size_t)(b * 255 + a * 85) * GG;
    float* __restrict__ dst = out + ((size_t)b * ROWS + 507 + (size_t)a * GG + s0) * 85;
    const int mis = (int)(((size_t)dst >> 2) & 3);
    const int t = threadIdx.x;

    // ---- Load phase: 42 channel-pairs x 13 float4 = 546 dual items ----
    vf4 A[3], B[3], L;
    const bool ok2 = (t + 512) < 546;
    #pragma unroll
    for (int k = 0; k < 3; ++k) {
        int i  = t + k * 256;
        int p  = i / 13;              // pair index (c = 2p)
        int w4 = i - p * 13;
        if (k < 2 || ok2) {
            const float* s = src + (size_t)(2 * p) * GG + s0 + w4 * 4;
            A[k] = *(const vf4*)(s);          // channel 2p
            B[k] = *(const vf4*)(s + GG);     // channel 2p+1
        }
    }
    const bool okL = (t >= 64) & (t < 77);    // leftover channel c=84
    if (okL) L = *(const vf4*)(src + (size_t)84 * GG + s0 + (t - 64) * 4);

    // ---- Write phase: adjacent-dword pairs -> ds_write2_b32 merge ----
    #pragma unroll
    for (int k = 0; k < 3; ++k) {
        if (k < 2 || ok2) {
            int i  = t + k * 256;
            int p  = i / 13;
            int w4 = i - p * 13;
            int base = mis + (w4 * 4) * 85 + 2 * p;
            if (p >= 2) {
                #pragma unroll
                for (int e = 0; e < 4; ++e) {
                    lds[base + e * 85]     = A[k][e];
                    lds[base + e * 85 + 1] = B[k][e];
                }
            } else if (p == 0) {      // c=0: bx, c=1: by
                #pragma unroll
                for (int e = 0; e < 4; ++e) {
                    int local = w4 * 4 + e;                   // 0..51
                    int gx = (local < G) ? local : local - G;
                    int gy = tile * 2 + ((local >= G) ? 1 : 0);
                    lds[base + e * 85]     = (fsig(A[k][e]) + (float)gx) * 16.0f;
                    lds[base + e * 85 + 1] = (fsig(B[k][e]) + (float)gy) * 16.0f;
                }
            } else {                  // p==1: c=2: bw, c=3: bh
                #pragma unroll
                for (int e = 0; e < 4; ++e) {
                    lds[base + e * 85]     = __expf(A[k][e]) * aw;
                    lds[base + e * 85 + 1] = __expf(B[k][e]) * ah;
                }
            }
        }
    }
    if (okL) {
        int base = mis + ((t - 64) * 4) * 85 + 84;
        #pragma unroll
        for (int e = 0; e < 4; ++e) lds[base + e * 85] = L[e];
    }
    __syncthreads();

    store_phase(lds, dst, mis, 52 * 85);
}

__device__ __forceinline__ void head13_body(
    const float* __restrict__ f, float* __restrict__ out, float* __restrict__ lds,
    int bid)
{
    constexpr int GG = 169, TPP = 4;
    const int tile = bid % TPP;
    const int ba   = bid / TPP;
    const int a    = ba % 3;
    const int b    = ba / 3;
    const int s0   = tile * 52;       // s0 % 13 == 0
    const int W    = (GG - s0 < 52) ? (GG - s0) : 52;   // 52,52,52,13

    const float aw = (a == 0) ? 81.f : (a == 1) ? 135.f : 344.f;
    const float ah = (a == 0) ? 82.f : (a == 1) ? 169.f : 319.f;

    const float* __restrict__ src = f + (size_t)(b * 255 + a * 85) * GG;
    float* __restrict__ dst = out + ((size_t)b * ROWS + (size_t)a * GG + s0) * 85;
    const int mis = (int)(((size_t)dst >> 2) & 3);
    const int t = threadIdx.x;

    // ---- Load phase: 42 pairs x 52 w = 2184 scalar-dual items, 9 rounds ----
    float A[9], B[9], Lv;
    #pragma unroll
    for (int k = 0; k < 9; ++k) {
        int i = t + k * 256;
        int p = i / 52;
        int w = i - p * 52;
        if ((k < 8 || i < 2184) && (w < W)) {
            const float* s = src + (size_t)(2 * p) * GG + s0 + w;
            A[k] = s[0];
            B[k] = s[GG];
        }
    }
    const bool okL = t < W;                   // leftover channel c=84
    if (okL) Lv = src[(size_t)84 * GG + s0 + t];

    // ---- Write phase ----
    #pragma unroll
    for (int k = 0; k < 9; ++k) {
        int i = t + k * 256;
        int p = i / 52;
        int w = i - p * 52;
        if ((k < 8 || i < 2184) && (w < W)) {
            int base = mis + w * 85 + 2 * p;
            if (p >= 2) {
                lds[base]     = A[k];
                lds[base + 1] = B[k];
            } else if (p == 0) {
                int t13 = w / 13;
                int gx  = w - t13 * 13;
                int gy  = tile * 4 + t13;
                lds[base]     = (fsig(A[k]) + (float)gx) * 32.0f;
                lds[base + 1] = (fsig(B[k]) + (float)gy) * 32.0f;
            } else {
                lds[base]     = __expf(A[k]) * aw;
                lds[base + 1] = __expf(B[k]) * ah;
            }
        }
    }
    if (okL) lds[mis + t * 85 + 84] = Lv;
    __syncthreads();

    store_phase(lds, dst, mis, W * 85);
}

__global__ __launch_bounds__(256, 8) void yolo_fused(
    const float* __restrict__ f13, const float* __restrict__ f26,
    float* __restrict__ out)
{
    __shared__ float lds[52 * 85 + 4];   // 17.7 KB -> 8 blocks/CU
    const int bid = blockIdx.x;
    if (bid < H26_BLOCKS) head26_body(f26, out, lds, bid);
    else                  head13_body(f13, out, lds, bid - H26_BLOCKS);
}

extern "C" void kernel_launch(void* const* d_in, const int* in_sizes, int n_in,
                              void* d_out, int out_size, void* d_ws, size_t ws_size,
                              hipStream_t stream) {
    const float* f13 = (const float*)d_in[0];
    const float* f26 = (const float*)d_in[1];
    float* out = (float*)d_out;
    yolo_fused<<<H26_BLOCKS + H13_BLOCKS, 256, 0, stream>>>(f13, f26, out);
}